// Round 4
// baseline (90.798 us; speedup 1.0000x reference)
//
#include <hip/hip_runtime.h>
#include <math.h>

#define B_  16
#define F_  64
#define C_  64
#define M_  512
#define OC_ 32
#define W_  16   // m-window per fused block

// ---------------------------------------------------------------------------
// k1: s[b,c,m] = mean_f x[b,f,c,m], m-split 4-ways for occupancy.
// grid = B*C*4 blocks (bc, q); 128 threads = (tf 0..3) x (tm 0..31).
// Emits rpart[bc*4+q] = sum_{m in 128-window} s[b,c,m] for the r-MLP.
// ---------------------------------------------------------------------------
__global__ __launch_bounds__(128, 6) void k1_mean(
    const float* __restrict__ x,
    float* __restrict__ s_out, float* __restrict__ rpart)
{
    const int gid = blockIdx.x;        // bc*4 + q
    const int q   = gid & 3;
    const int bc  = gid >> 2;
    const int b   = bc >> 6;
    const int c   = bc & 63;
    const int t   = threadIdx.x;
    const int tf  = t >> 5;            // 0..3 -> f chunk
    const int tm  = t & 31;            // float4 column within window
    const int m4  = (q << 5) + tm;     // global float4 index 0..127

    const size_t rowbase = ((size_t)b * F_ * C_ + c) * M_;   // + f*C*M
    float ax = 0.f, ay = 0.f, az = 0.f, aw = 0.f;
    #pragma unroll 8
    for (int j = 0; j < 16; ++j) {
        const int f = (tf << 4) + j;
        const float4 v = ((const float4*)(x + rowbase + (size_t)f * C_ * M_))[m4];
        ax += v.x; ay += v.y; az += v.z; aw += v.w;
    }

    __shared__ float4 red[4][32];
    red[tf][tm] = make_float4(ax, ay, az, aw);
    __syncthreads();

    if (tf == 0) {                     // lanes 0..31 of wave 0
        const float4 r1 = red[1][tm], r2 = red[2][tm], r3 = red[3][tm];
        const float inv_f = 1.0f / (float)F_;
        float4 sv;
        sv.x = (ax + r1.x + r2.x + r3.x) * inv_f;
        sv.y = (ay + r1.y + r2.y + r3.y) * inv_f;
        sv.z = (az + r1.z + r2.z + r3.z) * inv_f;
        sv.w = (aw + r1.w + r2.w + r3.w) * inv_f;
        ((float4*)(s_out + (size_t)bc * M_))[m4] = sv;

        float p = sv.x + sv.y + sv.z + sv.w;
        #pragma unroll
        for (int off = 16; off > 0; off >>= 1) p += __shfl_xor(p, off);
        if (t == 0) rpart[gid] = p;
    }
}

// ---------------------------------------------------------------------------
// k2_fused: block = (b, 16-m window). Double-buffered A tiles; computes
// snew for 64 c x 16 m into LDS, then writes the 32-channel pointwise
// expansion directly (coalesced full-line float4 stores). Replaces k2+k3:
// no snew roundtrip, out-writes overlap A-reads.
// ---------------------------------------------------------------------------
__global__ __launch_bounds__(256) void k2_fused(
    const float* __restrict__ A, const float* __restrict__ phys,
    const float* __restrict__ kappa_p, const float* __restrict__ alpha_p,
    const float* __restrict__ s_in, const float* __restrict__ rpart,
    const float* __restrict__ w1, const float* __restrict__ b1,
    const float* __restrict__ w2, const float* __restrict__ b2,
    const float* __restrict__ pw, const float* __restrict__ pb,
    float* __restrict__ out)
{
    __shared__ float Al[2][C_ * 65];     // double-buffered A tile (pad 65)
    __shared__ float s_l[C_][W_ + 1];    // s window  (pad 17)
    __shared__ float ph_l[C_][W_ + 1];   // phys window
    __shared__ float sn_l[C_][W_ + 1];   // snew window
    __shared__ float redD[4][C_];
    __shared__ float redA[4][C_];

    const int blk = blockIdx.x;          // b*32 + mc
    const int b   = blk >> 5;
    const int m0  = (blk & 31) << 4;     // window start
    const int t   = threadIdx.x;         // 0..255
    const int c   = t & 63;
    const int q   = t >> 6;              // wave id = quarter

    // ---- stage s/phys windows: 64 rows x 64 B (exactly line-granular) ----
    {
        const int rr = t >> 2;           // row 0..63
        const int mq = (t & 3) << 2;     // m quad 0,4,8,12
        const size_t g = ((size_t)b * C_ + rr) * M_ + m0 + mq;
        const float4 sv = *(const float4*)(s_in + g);
        const float4 pv = *(const float4*)(phys + g);
        s_l[rr][mq + 0] = sv.x; s_l[rr][mq + 1] = sv.y;
        s_l[rr][mq + 2] = sv.z; s_l[rr][mq + 3] = sv.w;
        ph_l[rr][mq + 0] = pv.x; ph_l[rr][mq + 1] = pv.y;
        ph_l[rr][mq + 2] = pv.z; ph_l[rr][mq + 3] = pv.w;
    }

    // ---- r-MLP (t<64 keeps r in a register) ----
    float r = 0.f;
    if (t < 64) {
        const float4 rp = ((const float4*)rpart)[b * C_ + t];
        const float rin = (rp.x + rp.y + rp.z + rp.w) * (1.0f / (float)M_);
        r = b2[0];
        #pragma unroll
        for (int j = 0; j < 16; ++j) {
            float h = rin * w1[j] + b1[j];
            h = (h > 0.f) ? h : (expf(h) - 1.f);   // ELU
            r += h * w2[j];
        }
    }

    // ---- stage A tile 0 ----
    const float* Abase = A + ((size_t)b * M_ + m0) * (C_ * C_);
    float4 pre[4];
    #pragma unroll
    for (int i = 0; i < 4; ++i) pre[i] = ((const float4*)Abase)[t + i * 256];
    #pragma unroll
    for (int i = 0; i < 4; ++i) {
        const int idx = t + i * 256;
        const int row = idx >> 4;
        const int col = (idx & 15) << 2;
        float* dst = &Al[0][row * 65 + col];
        dst[0] = pre[i].x; dst[1] = pre[i].y; dst[2] = pre[i].z; dst[3] = pre[i].w;
    }
    __syncthreads();

    const float k  = log1pf(expf(kappa_p[0]));     // softplus(kappa)
    const float al = alpha_p[0];

    for (int mi = 0; mi < W_; ++mi) {
        const int cur = mi & 1;

        // prefetch next A tile into registers (latency hides under reduce)
        if (mi < W_ - 1) {
            const float4* Ap = (const float4*)(Abase + (size_t)(mi + 1) * (C_ * C_));
            #pragma unroll
            for (int i = 0; i < 4; ++i) pre[i] = Ap[t + i * 256];
        }

        // quarter reductions on current tile
        float dpart = 0.f, apart = 0.f;
        const int j0 = q << 4;
        #pragma unroll
        for (int j = 0; j < 16; ++j) {
            dpart += Al[cur][c * 65 + (j0 + j)];               // row c
            apart += Al[cur][(j0 + j) * 65 + c] * s_l[j0 + j][mi]; // col c
        }
        redD[q][c] = dpart;
        redA[q][c] = apart;
        __syncthreads();

        if (t < 64) {
            const float deg  = redD[0][t] + redD[1][t] + redD[2][t] + redD[3][t];
            const float As   = redA[0][t] + redA[1][t] + redA[2][t] + redA[3][t];
            const float sval = s_l[t][mi];
            const float Ls   = deg * sval - As;
            sn_l[t][mi] = sval - k * Ls + (r + al * ph_l[t][mi]);
        }

        // write prefetched tile into the other buffer
        if (mi < W_ - 1) {
            #pragma unroll
            for (int i = 0; i < 4; ++i) {
                const int idx = t + i * 256;
                const int row = idx >> 4;
                const int col = (idx & 15) << 2;
                float* dst = &Al[cur ^ 1][row * 65 + col];
                dst[0] = pre[i].x; dst[1] = pre[i].y;
                dst[2] = pre[i].z; dst[3] = pre[i].w;
            }
        }
        __syncthreads();
    }

    // ---- 32-channel expansion: thread owns (row rr, m-quad mq) ----
    {
        const int rr = t >> 2;
        const int mq = (t & 3) << 2;
        const float v0 = sn_l[rr][mq + 0];
        const float v1 = sn_l[rr][mq + 1];
        const float v2 = sn_l[rr][mq + 2];
        const float v3 = sn_l[rr][mq + 3];
        const size_t obase = (((size_t)b * OC_) * C_ + rr) * M_ + m0 + mq;
        #pragma unroll 4
        for (int o = 0; o < OC_; ++o) {
            const float w  = pw[o];
            const float bb = pb[o];
            float4 ov;
            ov.x = v0 * w + bb; ov.y = v1 * w + bb;
            ov.z = v2 * w + bb; ov.w = v3 * w + bb;
            *(float4*)(out + obase + (size_t)o * (C_ * M_)) = ov;
        }
    }
}

extern "C" void kernel_launch(void* const* d_in, const int* in_sizes, int n_in,
                              void* d_out, int out_size, void* d_ws, size_t ws_size,
                              hipStream_t stream)
{
    const float* x     = (const float*)d_in[0];
    const float* A     = (const float*)d_in[1];
    const float* phys  = (const float*)d_in[2];
    const float* kappa = (const float*)d_in[3];
    const float* alpha = (const float*)d_in[4];
    const float* w1    = (const float*)d_in[5];
    const float* b1    = (const float*)d_in[6];
    const float* w2    = (const float*)d_in[7];
    const float* b2    = (const float*)d_in[8];
    const float* pw    = (const float*)d_in[9];
    const float* pb    = (const float*)d_in[10];
    float* out = (float*)d_out;

    float* ws    = (float*)d_ws;
    float* s     = ws;                          // B*C*M
    float* rpart = ws + (size_t)B_ * C_ * M_;   // B*C*4 (16B-aligned)

    k1_mean<<<B_ * C_ * 4, 128, 0, stream>>>(x, s, rpart);
    k2_fused<<<B_ * (M_ / W_), 256, 0, stream>>>(A, phys, kappa, alpha, s, rpart,
                                                 w1, b1, w2, b2, pw, pb, out);
}

// Round 5
// 77.548 us; speedup vs baseline: 1.1709x; 1.1709x over previous
//
#include <hip/hip_runtime.h>
#include <math.h>

#define B_  16
#define F_  64
#define C_  64
#define M_  512
#define OC_ 32

// ---------------------------------------------------------------------------
// k1: s[b,c,m] = mean_f x[b,f,c,m], m-split 4-ways for occupancy.
// grid = B*C*4 blocks (bc, q); 128 threads = (tf 0..3) x (tm 0..31).
// Emits rpart[bc*4+q] = sum_{m in 128-window} s[b,c,m] for the r-MLP.
// ---------------------------------------------------------------------------
__global__ __launch_bounds__(128, 6) void k1_mean(
    const float* __restrict__ x,
    float* __restrict__ s_out, float* __restrict__ rpart)
{
    const int gid = blockIdx.x;        // bc*4 + q
    const int q   = gid & 3;
    const int bc  = gid >> 2;
    const int b   = bc >> 6;
    const int c   = bc & 63;
    const int t   = threadIdx.x;
    const int tf  = t >> 5;            // 0..3 -> f chunk
    const int tm  = t & 31;            // float4 column within window
    const int m4  = (q << 5) + tm;     // global float4 index 0..127

    const size_t rowbase = ((size_t)b * F_ * C_ + c) * M_;   // + f*C*M
    float ax = 0.f, ay = 0.f, az = 0.f, aw = 0.f;
    #pragma unroll 8
    for (int j = 0; j < 16; ++j) {
        const int f = (tf << 4) + j;
        const float4 v = ((const float4*)(x + rowbase + (size_t)f * C_ * M_))[m4];
        ax += v.x; ay += v.y; az += v.z; aw += v.w;
    }

    __shared__ float4 red[4][32];
    red[tf][tm] = make_float4(ax, ay, az, aw);
    __syncthreads();

    if (tf == 0) {                     // lanes 0..31 of wave 0
        const float4 r1 = red[1][tm], r2 = red[2][tm], r3 = red[3][tm];
        const float inv_f = 1.0f / (float)F_;
        float4 sv;
        sv.x = (ax + r1.x + r2.x + r3.x) * inv_f;
        sv.y = (ay + r1.y + r2.y + r3.y) * inv_f;
        sv.z = (az + r1.z + r2.z + r3.z) * inv_f;
        sv.w = (aw + r1.w + r2.w + r3.w) * inv_f;
        ((float4*)(s_out + (size_t)bc * M_))[m4] = sv;

        float p = sv.x + sv.y + sv.z + sv.w;
        #pragma unroll
        for (int off = 16; off > 0; off >>= 1) p += __shfl_xor(p, off);
        if (t == 0) rpart[gid] = p;
    }
}

// ---------------------------------------------------------------------------
// k2 v4: barrier-free per-wave tiles. Block = (b, 4-m window), 4 waves;
// wave w owns tile (b, m0+w) entirely: 16 coalesced float4 loads into
// registers (16 KB in flight per wave), then in-register shuffle
// reduce-scatter for deg (over h bits 8/4/2/1) and As = A^T s (over g bits
// 16/32). Lane l=(g,h) ends holding deg_i and As_i for i = 4h+g.
// s/phys/snew go through pad-5 LDS windows (conflict-free, float4 global).
// 2048 blocks, 2 barriers/block total, no A staging in LDS.
// ---------------------------------------------------------------------------
__global__ __launch_bounds__(256, 4) void k2_laplace(
    const float* __restrict__ A, const float* __restrict__ phys,
    const float* __restrict__ kappa_p, const float* __restrict__ alpha_p,
    const float* __restrict__ s_in, const float* __restrict__ rpart,
    const float* __restrict__ w1, const float* __restrict__ b1,
    const float* __restrict__ w2, const float* __restrict__ b2,
    float* __restrict__ snew)
{
    __shared__ float s_l[C_ * 5];    // [c][mrel], pad 5 (bijective mod 32)
    __shared__ float ph_l[C_ * 5];
    __shared__ float sn_l[C_ * 5];
    __shared__ float r_l[C_];

    const int blk = blockIdx.x;      // b*128 + mw
    const int b   = blk >> 7;
    const int m0  = (blk & 127) << 2;
    const int t   = threadIdx.x;     // 0..255

    // ---- stage: s window | phys window | r-MLP (one wave each) ----
    if (t < 64) {
        const float4 sv = *(const float4*)(s_in + ((size_t)(b * C_ + t)) * M_ + m0);
        s_l[t*5+0] = sv.x; s_l[t*5+1] = sv.y; s_l[t*5+2] = sv.z; s_l[t*5+3] = sv.w;
    } else if (t < 128) {
        const int tt = t - 64;
        const float4 pv = *(const float4*)(phys + ((size_t)(b * C_ + tt)) * M_ + m0);
        ph_l[tt*5+0] = pv.x; ph_l[tt*5+1] = pv.y; ph_l[tt*5+2] = pv.z; ph_l[tt*5+3] = pv.w;
    } else if (t < 192) {
        const int tt = t - 128;
        const float4 rp = ((const float4*)rpart)[b * C_ + tt];
        const float rin = (rp.x + rp.y + rp.z + rp.w) * (1.0f / (float)M_);
        float r = b2[0];
        #pragma unroll
        for (int j = 0; j < 16; ++j) {
            float hh = rin * w1[j] + b1[j];
            hh = (hh > 0.f) ? hh : (expf(hh) - 1.f);   // ELU
            r += hh * w2[j];
        }
        r_l[tt] = r;
    }
    __syncthreads();

    const int w = t >> 6;            // wave -> m = m0 + w, mrel = w
    const int l = t & 63;
    const int g = l >> 4;            // 0..3
    const int h = l & 15;            // 0..15

    // ---- load my tile: lane l gets row 4j+g, cols 4h..4h+3, for j=0..15 ----
    const float4* Ap = (const float4*)(A + ((size_t)(b * M_ + m0 + w)) * (C_ * C_));
    float4 v[16];
    #pragma unroll
    for (int j = 0; j < 16; ++j) v[j] = Ap[j * 64 + l];

    // ---- per-lane partials ----
    float d[16];                     // d[j]: partial deg of row 4j+g
    float a0 = 0.f, a1 = 0.f, a2 = 0.f, a3 = 0.f;  // partial As of col 4h+k
    #pragma unroll
    for (int j = 0; j < 16; ++j) {
        const float sr = s_l[(4*j + g) * 5 + w];   // s[row], 16-lane broadcast
        d[j] = v[j].x + v[j].y + v[j].z + v[j].w;
        a0 += sr * v[j].x; a1 += sr * v[j].y;
        a2 += sr * v[j].z; a3 += sr * v[j].w;
    }

    // ---- deg reduce-scatter over h (keep j == h) ----
    float e[8];
    #pragma unroll
    for (int jj = 0; jj < 8; ++jj) {
        const float sd = (h & 8) ? d[jj] : d[jj + 8];
        const float rv = __shfl_xor(sd, 8);
        e[jj] = ((h & 8) ? d[jj + 8] : d[jj]) + rv;
    }
    float f2[4];
    #pragma unroll
    for (int jj = 0; jj < 4; ++jj) {
        const float sd = (h & 4) ? e[jj] : e[jj + 4];
        const float rv = __shfl_xor(sd, 4);
        f2[jj] = ((h & 4) ? e[jj + 4] : e[jj]) + rv;
    }
    float g2[2];
    #pragma unroll
    for (int jj = 0; jj < 2; ++jj) {
        const float sd = (h & 2) ? f2[jj] : f2[jj + 2];
        const float rv = __shfl_xor(sd, 2);
        g2[jj] = ((h & 2) ? f2[jj + 2] : f2[jj]) + rv;
    }
    float deg;
    {
        const float sd = (h & 1) ? g2[0] : g2[1];
        const float rv = __shfl_xor(sd, 1);
        deg = ((h & 1) ? g2[1] : g2[0]) + rv;      // deg of row 4h+g
    }

    // ---- As reduce-scatter over g (keep k == g) ----
    const float send0 = (g & 1) ? a0 : a1;
    const float send1 = (g & 1) ? a2 : a3;
    const float r0 = __shfl_xor(send0, 16);
    const float r1 = __shfl_xor(send1, 16);
    const float b0v = ((g & 1) ? a1 : a0) + r0;    // k = (g&1)
    const float b1v = ((g & 1) ? a3 : a2) + r1;    // k = (g&1)+2
    const float send2 = (g & 2) ? b0v : b1v;
    const float r2 = __shfl_xor(send2, 32);
    const float Asv = ((g & 2) ? b1v : b0v) + r2;  // As of col 4h+g

    // ---- snew for i = 4h+g at m = m0+w ----
    const float kk = log1pf(expf(kappa_p[0]));     // softplus(kappa)
    const float al = alpha_p[0];
    const int   i  = 4 * h + g;
    const float sval = s_l[i * 5 + w];
    const float Ls   = deg * sval - Asv;
    sn_l[i * 5 + w]  = sval - kk * Ls + (r_l[i] + al * ph_l[i * 5 + w]);
    __syncthreads();

    // ---- coalesced float4 snew write ----
    if (t < 64) {
        float4 ov;
        ov.x = sn_l[t*5+0]; ov.y = sn_l[t*5+1];
        ov.z = sn_l[t*5+2]; ov.w = sn_l[t*5+3];
        *(float4*)(snew + ((size_t)(b * C_ + t)) * M_ + m0) = ov;
    }
}

// ---------------------------------------------------------------------------
// k3: out[b,o,c,m] = s_new[b,c,m]*pw[o] + pb[o]  (pure bandwidth, float4)
// ---------------------------------------------------------------------------
__global__ __launch_bounds__(256) void k3_expand(
    const float* __restrict__ snew,
    const float* __restrict__ pw, const float* __restrict__ pb,
    float* __restrict__ out)
{
    const int n4 = (B_ * OC_ * C_ * M_) / 4;   // 4,194,304
    for (int i = blockIdx.x * blockDim.x + threadIdx.x; i < n4;
         i += gridDim.x * blockDim.x) {
        const int m4 = i & 127;          // M/4 = 128
        const int c  = (i >> 7) & 63;
        const int o  = (i >> 13) & 31;
        const int b  = i >> 18;
        const float4 v = ((const float4*)snew)[(((b << 6) + c) << 7) + m4];
        const float w  = pw[o];
        const float bb = pb[o];
        float4 r;
        r.x = v.x * w + bb; r.y = v.y * w + bb;
        r.z = v.z * w + bb; r.w = v.w * w + bb;
        ((float4*)out)[i] = r;
    }
}

extern "C" void kernel_launch(void* const* d_in, const int* in_sizes, int n_in,
                              void* d_out, int out_size, void* d_ws, size_t ws_size,
                              hipStream_t stream)
{
    const float* x     = (const float*)d_in[0];
    const float* A     = (const float*)d_in[1];
    const float* phys  = (const float*)d_in[2];
    const float* kappa = (const float*)d_in[3];
    const float* alpha = (const float*)d_in[4];
    const float* w1    = (const float*)d_in[5];
    const float* b1    = (const float*)d_in[6];
    const float* w2    = (const float*)d_in[7];
    const float* b2    = (const float*)d_in[8];
    const float* pw    = (const float*)d_in[9];
    const float* pb    = (const float*)d_in[10];
    float* out = (float*)d_out;

    float* ws    = (float*)d_ws;
    float* s     = ws;                            // B*C*M
    float* snew  = ws + (size_t)B_ * C_ * M_;     // B*C*M
    float* rpart = ws + (size_t)2 * B_ * C_ * M_; // B*C*4 (16B-aligned)

    k1_mean<<<B_ * C_ * 4, 128, 0, stream>>>(x, s, rpart);
    k2_laplace<<<B_ * (M_ / 4), 256, 0, stream>>>(A, phys, kappa, alpha, s, rpart,
                                                  w1, b1, w2, b2, snew);
    k3_expand<<<2048, 256, 0, stream>>>(snew, pw, pb, out);
}